// Round 1
// baseline (134.912 us; speedup 1.0000x reference)
//
#include <hip/hip_runtime.h>

// GatedBlock: RS = [(256,0),(128,1),(64,2),(32,3)]
// SIZE_OUT = 256 + 384 + 320 + 224 = 1184, N_GATES = 224, ROW_IN = 1408
// Output col c mapping:
//   c in [0,256)    : relu(x)
//   c in [256,640)  : x * sigmoid(gate[(c-256)/3])
//   c in [640,960)  : x * sigmoid(gate[128 + (c-640)/5])
//   c in [960,1184) : x * sigmoid(gate[192 + (c-960)/7])
// gates live at input row offset 1184.
// All boundaries divisible by 4 -> each output float4 stays in one segment.

#define SIZE_OUT 1184
#define ROW_IN   1408
#define N_F4     296   // SIZE_OUT / 4

__device__ __forceinline__ float fast_sigmoid(float x) {
    return 1.0f / (1.0f + __expf(-x));
}

__global__ __launch_bounds__(256) void gated_block_kernel(
    const float* __restrict__ in, float* __restrict__ out, long long total4)
{
    long long stride = (long long)gridDim.x * blockDim.x;
    for (long long idx = (long long)blockIdx.x * blockDim.x + threadIdx.x;
         idx < total4; idx += stride)
    {
        int row = (int)(idx / N_F4);
        int c4  = (int)(idx - (long long)row * N_F4);
        const float* __restrict__ rin = in + (long long)row * ROW_IN;

        float4 v = reinterpret_cast<const float4*>(rin)[c4];
        float* vf = reinterpret_cast<float*>(&v);

        if (c4 < 64) {
            // l=0 scalars: relu
            #pragma unroll
            for (int j = 0; j < 4; ++j) vf[j] = fmaxf(vf[j], 0.0f);
        } else {
            const float* __restrict__ gates = rin + SIZE_OUT;
            int c = c4 * 4;
            int off, d, gbase;
            if (c4 < 160)      { off = c - 256; d = 3; gbase = 0;   }
            else if (c4 < 240) { off = c - 640; d = 5; gbase = 128; }
            else               { off = c - 960; d = 7; gbase = 192; }
            #pragma unroll
            for (int j = 0; j < 4; ++j) {
                int g = gbase + (off + j) / d;   // const-divisor -> magic mul
                vf[j] *= fast_sigmoid(gates[g]);
            }
        }
        reinterpret_cast<float4*>(out)[idx] = v;
    }
}

extern "C" void kernel_launch(void* const* d_in, const int* in_sizes, int n_in,
                              void* d_out, int out_size, void* d_ws, size_t ws_size,
                              hipStream_t stream)
{
    const float* in = (const float*)d_in[0];
    float* out = (float*)d_out;

    long long total4 = (long long)out_size / 4;   // 65536 * 296
    int block = 256;
    // memory-bound: modest grid + grid-stride (G11)
    long long want = (total4 + block - 1) / block;
    int grid = (int)(want < 4096 ? want : 4096);

    gated_block_kernel<<<grid, block, 0, stream>>>(in, out, total4);
}

// Round 2
// 120.218 us; speedup vs baseline: 1.1222x; 1.1222x over previous
//
#include <hip/hip_runtime.h>

// GatedBlock: RS = [(256,0),(128,1),(64,2),(32,3)]
// SIZE_OUT = 256 + 384 + 320 + 224 = 1184, N_GATES = 224, ROW_IN = 1408
// Output col c mapping:
//   c in [0,256)    : relu(x)
//   c in [256,640)  : x * sigmoid(gate[(c-256)/3])
//   c in [640,960)  : x * sigmoid(gate[128 + (c-640)/5])
//   c in [960,1184) : x * sigmoid(gate[192 + (c-960)/7])
// gates live at input row offset 1184.
// All boundaries divisible by 4 -> each output float4 stays in one segment.

#define SIZE_OUT 1184
#define ROW_IN   1408
#define N_F4     296   // SIZE_OUT / 4

typedef float f32x4 __attribute__((ext_vector_type(4)));

__device__ __forceinline__ float fast_sigmoid(float x) {
    return 1.0f / (1.0f + __expf(-x));
}

__global__ __launch_bounds__(256) void gated_block_kernel(
    const float* __restrict__ in, float* __restrict__ out, int total4)
{
    int stride = gridDim.x * blockDim.x;
    for (int idx = blockIdx.x * blockDim.x + threadIdx.x;
         idx < total4; idx += stride)
    {
        unsigned row = (unsigned)idx / N_F4;        // 32-bit magic mul
        int c4  = idx - (int)(row * N_F4);
        const float* __restrict__ rin = in + (long long)row * ROW_IN;

        // streamed data: nontemporal (read-once, don't pollute caches)
        f32x4 v = __builtin_nontemporal_load(
            reinterpret_cast<const f32x4*>(rin) + c4);

        if (c4 < 64) {
            // l=0 scalars: relu
            #pragma unroll
            for (int j = 0; j < 4; ++j) v[j] = fmaxf(v[j], 0.0f);
        } else {
            const float* __restrict__ gates = rin + SIZE_OUT;
            int c = c4 * 4;
            int off, d, gbase;
            if (c4 < 160)      { off = c - 256; d = 3; gbase = 0;   }
            else if (c4 < 240) { off = c - 640; d = 5; gbase = 128; }
            else               { off = c - 960; d = 7; gbase = 192; }
            #pragma unroll
            for (int j = 0; j < 4; ++j) {
                int g = gbase + (off + j) / d;   // const-divisor -> magic mul
                // gates are REUSED (3-7x) -> normal cached load
                v[j] *= fast_sigmoid(gates[g]);
            }
        }
        // write-once output: nontemporal store
        __builtin_nontemporal_store(v, reinterpret_cast<f32x4*>(out) + idx);
    }
}

extern "C" void kernel_launch(void* const* d_in, const int* in_sizes, int n_in,
                              void* d_out, int out_size, void* d_ws, size_t ws_size,
                              hipStream_t stream)
{
    const float* in = (const float*)d_in[0];
    float* out = (float*)d_out;

    int total4 = out_size / 4;   // 65536 * 296 = 19,398,656
    int block = 256;
    long long want = ((long long)total4 + block - 1) / block;
    int grid = (int)(want < 4096 ? want : 4096);

    gated_block_kernel<<<grid, block, 0, stream>>>(in, out, total4);
}